// Round 2
// baseline (288.816 us; speedup 1.0000x reference)
//
#include <hip/hip_runtime.h>
#include <math.h>

// Problem constants (N,L,C)=(4,1024,512), H=16, D=32, S=16
#define NB 4
#define LB 1024
#define CB 512
#define HH 16
#define DD 32
#define SS 16
#define NL (NB*LB)      // 4096 rows
#define C3 (3*CB)       // 1536

// bi arrives as int32 (harness: "integer -> const int*"; JAX x64-off makes
// the reference's int64 cast a no-op to int32 anyway).
__device__ __forceinline__ int lower_bound_i32(const int* a, int n, int v) {
  int lo = 0, hi = n;
  while (lo < hi) { int mid = (lo + hi) >> 1; if (a[mid] < v) lo = mid + 1; else hi = mid; }
  return lo;
}

// ---------------------------------------------------------------------------
// Tiled fp32 GEMM: Co[m][n] = epilogue( sum_k A[m][k]*B[n][k] )
// 64x64 tile, 256 threads, 4x4 microtile, K-tile 16.
// MODE 0: qkv projection, fused phi (elu(z)+1) on q,k columns (n < 2C)
// MODE 1: + bias, exact gelu
// MODE 2: + bias + residual
// ---------------------------------------------------------------------------
template<int MODE>
__global__ __launch_bounds__(256) void gemm_nt(
    const float* __restrict__ A, const float* __restrict__ B, float* __restrict__ Co,
    int M, int Nn, int K,
    const float* __restrict__ bias, const float* __restrict__ res)
{
  __shared__ float As[16][68];   // k-major; row stride 68 floats = 272 B (16B aligned)
  __shared__ float Bs[16][68];
  const int tid = threadIdx.x;
  const int tx = tid & 15, ty = tid >> 4;
  const int bm = blockIdx.x * 64, bn = blockIdx.y * 64;
  const int lr = tid >> 2;          // 0..63 tile row
  const int lk = (tid & 3) * 4;     // 0,4,8,12 k-offset
  const float* Aptr = A + (long)(bm + lr) * K + lk;
  const float* Bptr = B + (long)(bn + lr) * K + lk;
  float acc[4][4] = {};
  for (int k0 = 0; k0 < K; k0 += 16) {
    const float4 a4 = *(const float4*)(Aptr + k0);
    const float4 b4 = *(const float4*)(Bptr + k0);
    if (k0) __syncthreads();
    As[lk+0][lr] = a4.x; As[lk+1][lr] = a4.y; As[lk+2][lr] = a4.z; As[lk+3][lr] = a4.w;
    Bs[lk+0][lr] = b4.x; Bs[lk+1][lr] = b4.y; Bs[lk+2][lr] = b4.z; Bs[lk+3][lr] = b4.w;
    __syncthreads();
    #pragma unroll
    for (int kk = 0; kk < 16; ++kk) {
      const float4 av = *(const float4*)&As[kk][ty*4];
      const float4 bv = *(const float4*)&Bs[kk][tx*4];
      const float aa[4] = {av.x, av.y, av.z, av.w};
      const float bb[4] = {bv.x, bv.y, bv.z, bv.w};
      #pragma unroll
      for (int i = 0; i < 4; ++i)
        #pragma unroll
        for (int j = 0; j < 4; ++j)
          acc[i][j] = fmaf(aa[i], bb[j], acc[i][j]);
    }
  }
  const float temp = 0.42044820762685725f;  // 32^-0.25
  #pragma unroll
  for (int i = 0; i < 4; ++i) {
    const int m = bm + ty*4 + i;
    #pragma unroll
    for (int j = 0; j < 4; ++j) {
      const int n = bn + tx*4 + j;
      float v = acc[i][j];
      if (MODE == 0) {
        if (n < 2*CB) { const float z = v * temp; v = (z > 0.f) ? (z + 1.f) : expf(z); }
      } else if (MODE == 1) {
        v += bias[n];
        v = v * 0.5f * (1.f + erff(v * 0.70710678118654752f));
      } else if (MODE == 2) {
        v += bias[n] + res[(long)m * Nn + n];
      }
      Co[(long)m * Nn + n] = v;
    }
  }
}

// ---------------------------------------------------------------------------
// Per (n,h,s): K_sum[d] = sum_l k[l][d], KV_sum[d][m] = sum_l k[l][d]*v[l][m]
// bi is sorted -> each segment is a contiguous l-range (binary search).
// ---------------------------------------------------------------------------
__global__ __launch_bounds__(256) void seg_sums(
    const float* __restrict__ qkv, const int* __restrict__ bi,
    float* __restrict__ segkv, float* __restrict__ segk)
{
  const int b = blockIdx.x;               // ((n*H+h)*S+s)
  const int s = b & (SS-1);
  const int h = (b >> 4) & (HH-1);
  const int n = b >> 8;
  __shared__ int sb[2];
  __shared__ float ks[8][DD];
  __shared__ float vs[8][DD];
  const int tid = threadIdx.x;
  if (tid == 0) {
    sb[0] = lower_bound_i32(bi, LB, s);
    sb[1] = lower_bound_i32(bi, LB, s + 1);
  }
  __syncthreads();
  const int lo = sb[0], hi = sb[1];
  const int li = tid >> 5, c = tid & 31;        // stage index
  const int d  = tid >> 3, m0 = (tid & 7) * 4;  // compute index
  float a0=0.f,a1=0.f,a2=0.f,a3=0.f, ksum=0.f;
  for (int l0 = lo; l0 < hi; l0 += 8) {
    const int l = l0 + li;
    __syncthreads();
    if (l < hi) {
      const float* row = qkv + (long)(n*LB + l) * C3;
      ks[li][c] = row[CB   + h*DD + c];
      vs[li][c] = row[2*CB + h*DD + c];
    } else {
      ks[li][c] = 0.f; vs[li][c] = 0.f;
    }
    __syncthreads();
    #pragma unroll
    for (int q = 0; q < 8; ++q) {
      const float kd = ks[q][d];
      ksum += kd;
      a0 = fmaf(kd, vs[q][m0+0], a0);
      a1 = fmaf(kd, vs[q][m0+1], a1);
      a2 = fmaf(kd, vs[q][m0+2], a2);
      a3 = fmaf(kd, vs[q][m0+3], a3);
    }
  }
  *(float4*)&segkv[(long)b*(DD*DD) + d*DD + m0] = make_float4(a0,a1,a2,a3);
  if ((tid & 7) == 0) segk[b*DD + d] = ksum;   // 8 threads share d; one stores
}

// ---------------------------------------------------------------------------
// Per (n,h,s): for each l in segment: t[l][m] = (q[l]·KV[:,m]) / (q[l]·K_sum)
// ---------------------------------------------------------------------------
__global__ __launch_bounds__(256) void seg_vout(
    const float* __restrict__ qkv, const int* __restrict__ bi,
    const float* __restrict__ segkv, const float* __restrict__ segk,
    float* __restrict__ tbuf)
{
  const int b = blockIdx.x;
  const int s = b & (SS-1);
  const int h = (b >> 4) & (HH-1);
  const int n = b >> 8;
  __shared__ float KVs[DD*DD];
  __shared__ float Ks[DD];
  __shared__ float qs[8][DD];
  __shared__ int sb[2];
  const int tid = threadIdx.x;
  if (tid == 0) {
    sb[0] = lower_bound_i32(bi, LB, s);
    sb[1] = lower_bound_i32(bi, LB, s + 1);
  }
  #pragma unroll
  for (int i = 0; i < 4; ++i) KVs[tid + i*256] = segkv[(long)b*(DD*DD) + tid + i*256];
  if (tid < DD) Ks[tid] = segk[b*DD + tid];
  __syncthreads();
  const int lo = sb[0], hi = sb[1];
  const int li = tid >> 5, m = tid & 31;
  for (int l0 = lo; l0 < hi; l0 += 8) {
    const int l = l0 + li;
    __syncthreads();
    if (l < hi) qs[li][m] = qkv[(long)(n*LB + l) * C3 + h*DD + m];
    __syncthreads();
    if (l < hi) {
      float vo = 0.f, den = 0.f;
      #pragma unroll
      for (int d2 = 0; d2 < DD; ++d2) {
        const float qd = qs[li][d2];
        vo  = fmaf(qd, KVs[d2*DD + m], vo);
        den = fmaf(qd, Ks[d2], den);
      }
      tbuf[(long)(n*LB + l) * CB + h*DD + m] = vo / den;
    }
  }
}

// ---------------------------------------------------------------------------
// Per row (n,l): beta = sigmoid([t,x,t-x]·w_beta); y = beta*x+(1-beta)*t;
// powernorm1(y) -> x1.  256 threads, 2 channels each; group = 32 channels
// = 16 consecutive lanes (within-wave shuffle reduce).
// ---------------------------------------------------------------------------
__global__ __launch_bounds__(256) void beta_pn1(
    const float* __restrict__ x, const float* __restrict__ tbuf,
    const float* __restrict__ w_beta,
    const float* __restrict__ pw, const float* __restrict__ pb, const float* __restrict__ pphi,
    float* __restrict__ x1)
{
  const int row = blockIdx.x;       // n*L + l
  const int tid = threadIdx.x;
  const int c0 = tid * 2;
  const long base = (long)row * CB;
  const float2 xv = *(const float2*)&x[base + c0];
  const float2 tv = *(const float2*)&tbuf[base + c0];
  float p = tv.x * w_beta[c0]   + xv.x * w_beta[CB + c0]   + (tv.x - xv.x) * w_beta[2*CB + c0]
          + tv.y * w_beta[c0+1] + xv.y * w_beta[CB + c0+1] + (tv.y - xv.y) * w_beta[2*CB + c0+1];
  #pragma unroll
  for (int off = 32; off >= 1; off >>= 1) p += __shfl_xor(p, off, 64);
  __shared__ float red[4];
  if ((tid & 63) == 0) red[tid >> 6] = p;
  __syncthreads();
  const float zsum = red[0] + red[1] + red[2] + red[3];
  const float beta = 1.f / (1.f + expf(-zsum));
  const float y0 = beta * xv.x + (1.f - beta) * tv.x;
  const float y1 = beta * xv.y + (1.f - beta) * tv.y;
  float ss = y0*y0 + y1*y1;
  #pragma unroll
  for (int off = 1; off < 16; off <<= 1) ss += __shfl_xor(ss, off, 64);  // 16 lanes = 32 ch
  const float inv = rsqrtf(ss * (1.f/32.f) + 1e-5f);
  const float o0 = y0 * inv * rsqrtf(pphi[c0]   + 1e-5f) * pw[c0]   + pb[c0];
  const float o1 = y1 * inv * rsqrtf(pphi[c0+1] + 1e-5f) * pw[c0+1] + pb[c0+1];
  *(float2*)&x1[base + c0] = make_float2(o0, o1);
}

// ---------------------------------------------------------------------------
// powernorm2(ffx) -> out
// ---------------------------------------------------------------------------
__global__ __launch_bounds__(256) void pn2_kernel(
    const float* __restrict__ ffx,
    const float* __restrict__ pw, const float* __restrict__ pb, const float* __restrict__ pphi,
    float* __restrict__ out)
{
  const int row = blockIdx.x;
  const int tid = threadIdx.x;
  const int c0 = tid * 2;
  const long base = (long)row * CB;
  const float2 yv = *(const float2*)&ffx[base + c0];
  float ss = yv.x*yv.x + yv.y*yv.y;
  #pragma unroll
  for (int off = 1; off < 16; off <<= 1) ss += __shfl_xor(ss, off, 64);
  const float inv = rsqrtf(ss * (1.f/32.f) + 1e-5f);
  const float o0 = yv.x * inv * rsqrtf(pphi[c0]   + 1e-5f) * pw[c0]   + pb[c0];
  const float o1 = yv.y * inv * rsqrtf(pphi[c0+1] + 1e-5f) * pw[c0+1] + pb[c0+1];
  *(float2*)&out[base + c0] = make_float2(o0, o1);
}

extern "C" void kernel_launch(void* const* d_in, const int* in_sizes, int n_in,
                              void* d_out, int out_size, void* d_ws, size_t ws_size,
                              hipStream_t stream)
{
  const float* x       = (const float*)d_in[0];
  const int*   bi      = (const int*)d_in[1];
  const float* w_qkv   = (const float*)d_in[2];
  const float* w_beta  = (const float*)d_in[3];
  const float* w1      = (const float*)d_in[4];
  const float* b1      = (const float*)d_in[5];
  const float* w2      = (const float*)d_in[6];
  const float* b2      = (const float*)d_in[7];
  const float* pn1_w   = (const float*)d_in[8];
  const float* pn1_b   = (const float*)d_in[9];
  const float* pn1_phi = (const float*)d_in[10];
  const float* pn2_w   = (const float*)d_in[11];
  const float* pn2_b   = (const float*)d_in[12];
  const float* pn2_phi = (const float*)d_in[13];
  float* out = (float*)d_out;
  float* ws  = (float*)d_ws;

  // workspace layout (floats) — total ~46.3 MB
  float* qkv   = ws;                               // 4096*1536 = 6,291,456
  float* segkv = qkv + (long)NL*C3;                // 4*16*16*1024 = 1,048,576
  float* segk  = segkv + (long)NB*HH*SS*DD*DD;     // 32,768
  float* tbuf  = segk + (long)NB*HH*SS*DD;         // 2,097,152
  float* x1    = tbuf + (long)NL*CB;               // 2,097,152
  float* h1    = qkv;                              // reuse qkv region (free after seg_vout)
  float* ffx   = qkv + (long)NL*CB;                // reuse (disjoint from h1)

  gemm_nt<0><<<dim3(NL/64, C3/64), 256, 0, stream>>>(x,  w_qkv, qkv, NL, C3, CB, nullptr, nullptr);
  seg_sums  <<<NB*HH*SS, 256, 0, stream>>>(qkv, bi, segkv, segk);
  seg_vout  <<<NB*HH*SS, 256, 0, stream>>>(qkv, bi, segkv, segk, tbuf);
  beta_pn1  <<<NL, 256, 0, stream>>>(x, tbuf, w_beta, pn1_w, pn1_b, pn1_phi, x1);
  gemm_nt<1><<<dim3(NL/64, CB/64), 256, 0, stream>>>(x1, w1, h1,  NL, CB, CB, b1, nullptr);
  gemm_nt<2><<<dim3(NL/64, CB/64), 256, 0, stream>>>(h1, w2, ffx, NL, CB, CB, b2, x1);
  pn2_kernel<<<NL, 256, 0, stream>>>(ffx, pn2_w, pn2_b, pn2_phi, out);
}

// Round 5
// 228.079 us; speedup vs baseline: 1.2663x; 1.2663x over previous
//
#include <hip/hip_runtime.h>
#include <math.h>

// Problem constants (N,L,C)=(4,1024,512), H=16, D=32, S=16
#define NB 4
#define LB 1024
#define CB 512
#define HH 16
#define DD 32
#define SS 16
#define NL (NB*LB)      // 4096 rows
#define C3 (3*CB)       // 1536

typedef __attribute__((ext_vector_type(8))) short short8;
typedef __attribute__((ext_vector_type(4))) float f32x4;

__device__ __forceinline__ unsigned short f2bf_rn(float f) {
  unsigned u = __builtin_bit_cast(unsigned, f);
  unsigned r = u + 0x7FFFu + ((u >> 16) & 1u);
  return (unsigned short)(r >> 16);
}
__device__ __forceinline__ float bf2f(unsigned short h) {
  unsigned u = ((unsigned)h) << 16;
  return __builtin_bit_cast(float, u);
}

__device__ __forceinline__ int lower_bound_i32(const int* a, int n, int v) {
  int lo = 0, hi = n;
  while (lo < hi) { int mid = (lo + hi) >> 1; if (a[mid] < v) lo = mid + 1; else hi = mid; }
  return lo;
}

// ---------------------------------------------------------------------------
// Split-bf16 MFMA GEMM: C[m][n] = epi( sum_k A[m][k]*B[n][k] ), A:[M][K], B:[N][K]
// x = hi + lo (bf16 each); C ~= Ah*Bh + Ah*Bl + Al*Bh  (~fp32 accuracy).
// 128 x BN tile, 4 waves (2x2), per-wave 64 x BN/2 = 4 x NJ frags of 16x16.
// LDS planes: [4 kchunks][rows][8] bf16 -> frag read = 1 contiguous b128,
// lanes 0-15 span 256B (2-way bank alias = free).
// MODE 0: qkv + phi on n<2C | MODE 1: +bias, gelu | MODE 2: +bias +residual
// ---------------------------------------------------------------------------
template<int MODE, int BN>
__global__ __launch_bounds__(256) void gemm_mfma(
    const float* __restrict__ A, const float* __restrict__ B, float* __restrict__ Co,
    int M, int Nn, int K,
    const float* __restrict__ bias, const float* __restrict__ res)
{
  constexpr int NJ = BN / 32;
  __shared__ short8 Ah8[4*128], Al8[4*128];
  __shared__ short8 Bh8[4*BN],  Bl8[4*BN];
  const int tid  = threadIdx.x;
  const int lane = tid & 63, wave = tid >> 6;
  const int wm = wave >> 1, wn = wave & 1;
  const int l15 = lane & 15, l4 = lane >> 4;
  const int bm = blockIdx.x * 128, bn = blockIdx.y * BN;

  f32x4 acc[4][NJ];
  #pragma unroll
  for (int i = 0; i < 4; ++i)
    #pragma unroll
    for (int j = 0; j < NJ; ++j)
      acc[i][j] = {0.f, 0.f, 0.f, 0.f};

  const int arow = tid >> 1, ah2 = tid & 1;       // 128 rows x 2 k-halves
  const float* Ag = A + (long)(bm + arow) * K + ah2 * 16;
  const int brow128 = tid >> 1, bh2 = tid & 1;    // BN=128 staging
  const int brow64  = tid >> 2, bq  = tid & 3;    // BN=64 staging
  const float* Bg = (BN == 128) ? (B + (long)(bn + brow128) * K + bh2 * 16)
                                : (B + (long)(bn + brow64)  * K + bq * 8);

  for (int k0 = 0; k0 < K; k0 += 32) {
    if (k0) __syncthreads();
    { // stage A: 16 fp32 per thread -> 2 kchunks x (hi8,lo8)
      const float4* g = (const float4*)(Ag + k0);
      const float4 q0 = g[0], q1 = g[1], q2 = g[2], q3 = g[3];
      const float f[16] = {q0.x,q0.y,q0.z,q0.w, q1.x,q1.y,q1.z,q1.w,
                           q2.x,q2.y,q2.z,q2.w, q3.x,q3.y,q3.z,q3.w};
      #pragma unroll
      for (int cc = 0; cc < 2; ++cc) {
        short8 hi, lo;
        #pragma unroll
        for (int e = 0; e < 8; ++e) {
          const float v = f[cc*8 + e];
          const unsigned short hb = f2bf_rn(v);
          hi[e] = (short)hb;
          lo[e] = (short)f2bf_rn(v - bf2f(hb));
        }
        const int idx = (ah2*2 + cc)*128 + arow;
        Ah8[idx] = hi; Al8[idx] = lo;
      }
    }
    if (BN == 128) { // stage B, 128 rows (same shape as A)
      const float4* g = (const float4*)(Bg + k0);
      const float4 q0 = g[0], q1 = g[1], q2 = g[2], q3 = g[3];
      const float f[16] = {q0.x,q0.y,q0.z,q0.w, q1.x,q1.y,q1.z,q1.w,
                           q2.x,q2.y,q2.z,q2.w, q3.x,q3.y,q3.z,q3.w};
      #pragma unroll
      for (int cc = 0; cc < 2; ++cc) {
        short8 hi, lo;
        #pragma unroll
        for (int e = 0; e < 8; ++e) {
          const float v = f[cc*8 + e];
          const unsigned short hb = f2bf_rn(v);
          hi[e] = (short)hb;
          lo[e] = (short)f2bf_rn(v - bf2f(hb));
        }
        const int idx = (bh2*2 + cc)*BN + brow128;
        Bh8[idx] = hi; Bl8[idx] = lo;
      }
    } else {        // stage B, 64 rows: 8 fp32 per thread -> 1 kchunk
      const float4* g = (const float4*)(Bg + k0);
      const float4 q0 = g[0], q1 = g[1];
      const float f[8] = {q0.x,q0.y,q0.z,q0.w, q1.x,q1.y,q1.z,q1.w};
      short8 hi, lo;
      #pragma unroll
      for (int e = 0; e < 8; ++e) {
        const float v = f[e];
        const unsigned short hb = f2bf_rn(v);
        hi[e] = (short)hb;
        lo[e] = (short)f2bf_rn(v - bf2f(hb));
      }
      const int idx = bq*BN + brow64;
      Bh8[idx] = hi; Bl8[idx] = lo;
    }
    __syncthreads();

    short8 bhf[NJ], blf[NJ];
    #pragma unroll
    for (int j = 0; j < NJ; ++j) {
      const int idx = l4*BN + wn*(NJ*16) + j*16 + l15;
      bhf[j] = Bh8[idx]; blf[j] = Bl8[idx];
    }
    #pragma unroll
    for (int i = 0; i < 4; ++i) {
      const int idx = l4*128 + wm*64 + i*16 + l15;
      const short8 ah = Ah8[idx], al = Al8[idx];
      #pragma unroll
      for (int j = 0; j < NJ; ++j) {
        acc[i][j] = __builtin_amdgcn_mfma_f32_16x16x32_bf16(ah, bhf[j], acc[i][j], 0, 0, 0);
        acc[i][j] = __builtin_amdgcn_mfma_f32_16x16x32_bf16(ah, blf[j], acc[i][j], 0, 0, 0);
        acc[i][j] = __builtin_amdgcn_mfma_f32_16x16x32_bf16(al, bhf[j], acc[i][j], 0, 0, 0);
      }
    }
  }

  const float temp = 0.42044820762685725f;  // 32^-0.25
  #pragma unroll
  for (int i = 0; i < 4; ++i) {
    #pragma unroll
    for (int j = 0; j < NJ; ++j) {
      const int n  = bn + wn*(NJ*16) + j*16 + l15;
      const int mb = bm + wm*64 + i*16 + l4*4;
      #pragma unroll
      for (int r = 0; r < 4; ++r) {
        const int m = mb + r;
        float v = acc[i][j][r];
        if (MODE == 0) {
          if (n < 2*CB) { const float z = v * temp; v = (z > 0.f) ? (z + 1.f) : expf(z); }
        } else if (MODE == 1) {
          v += bias[n];
          v = v * 0.5f * (1.f + erff(v * 0.70710678118654752f));
        } else {
          v += bias[n] + res[(long)m * Nn + n];
        }
        Co[(long)m * Nn + n] = v;
      }
    }
  }
}

// ---------------------------------------------------------------------------
// Per (n,h,s): K_sum[d] = sum_l k[l][d], KV_sum[d][m] = sum_l k[l][d]*v[l][m]
// ---------------------------------------------------------------------------
__global__ __launch_bounds__(256) void seg_sums(
    const float* __restrict__ qkv, const int* __restrict__ bi,
    float* __restrict__ segkv, float* __restrict__ segk)
{
  const int b = blockIdx.x;               // ((n*H+h)*S+s)
  const int s = b & (SS-1);
  const int h = (b >> 4) & (HH-1);
  const int n = b >> 8;
  __shared__ int sb[2];
  __shared__ float ks[8][DD];
  __shared__ float vs[8][DD];
  const int tid = threadIdx.x;
  if (tid == 0) {
    sb[0] = lower_bound_i32(bi, LB, s);
    sb[1] = lower_bound_i32(bi, LB, s + 1);
  }
  __syncthreads();
  const int lo = sb[0], hi = sb[1];
  const int li = tid >> 5, c = tid & 31;
  const int d  = tid >> 3, m0 = (tid & 7) * 4;
  float a0=0.f,a1=0.f,a2=0.f,a3=0.f, ksum=0.f;
  for (int l0 = lo; l0 < hi; l0 += 8) {
    const int l = l0 + li;
    __syncthreads();
    if (l < hi) {
      const float* row = qkv + (long)(n*LB + l) * C3;
      ks[li][c] = row[CB   + h*DD + c];
      vs[li][c] = row[2*CB + h*DD + c];
    } else {
      ks[li][c] = 0.f; vs[li][c] = 0.f;
    }
    __syncthreads();
    #pragma unroll
    for (int q = 0; q < 8; ++q) {
      const float kd = ks[q][d];
      ksum += kd;
      a0 = fmaf(kd, vs[q][m0+0], a0);
      a1 = fmaf(kd, vs[q][m0+1], a1);
      a2 = fmaf(kd, vs[q][m0+2], a2);
      a3 = fmaf(kd, vs[q][m0+3], a3);
    }
  }
  *(float4*)&segkv[(long)b*(DD*DD) + d*DD + m0] = make_float4(a0,a1,a2,a3);
  if ((tid & 7) == 0) segk[b*DD + d] = ksum;
}

// ---------------------------------------------------------------------------
// Per (n,h,s): t[l][m] = (q[l]·KV[:,m]) / (q[l]·K_sum)
// ---------------------------------------------------------------------------
__global__ __launch_bounds__(256) void seg_vout(
    const float* __restrict__ qkv, const int* __restrict__ bi,
    const float* __restrict__ segkv, const float* __restrict__ segk,
    float* __restrict__ tbuf)
{
  const int b = blockIdx.x;
  const int s = b & (SS-1);
  const int h = (b >> 4) & (HH-1);
  const int n = b >> 8;
  __shared__ float KVs[DD*DD];
  __shared__ float Ks[DD];
  __shared__ float qs[8][DD];
  __shared__ int sb[2];
  const int tid = threadIdx.x;
  if (tid == 0) {
    sb[0] = lower_bound_i32(bi, LB, s);
    sb[1] = lower_bound_i32(bi, LB, s + 1);
  }
  #pragma unroll
  for (int i = 0; i < 4; ++i) KVs[tid + i*256] = segkv[(long)b*(DD*DD) + tid + i*256];
  if (tid < DD) Ks[tid] = segk[b*DD + tid];
  __syncthreads();
  const int lo = sb[0], hi = sb[1];
  const int li = tid >> 5, m = tid & 31;
  for (int l0 = lo; l0 < hi; l0 += 8) {
    const int l = l0 + li;
    __syncthreads();
    if (l < hi) qs[li][m] = qkv[(long)(n*LB + l) * C3 + h*DD + m];
    __syncthreads();
    if (l < hi) {
      float vo = 0.f, den = 0.f;
      #pragma unroll
      for (int d2 = 0; d2 < DD; ++d2) {
        const float qd = qs[li][d2];
        vo  = fmaf(qd, KVs[d2*DD + m], vo);
        den = fmaf(qd, Ks[d2], den);
      }
      tbuf[(long)(n*LB + l) * CB + h*DD + m] = vo / den;
    }
  }
}

// ---------------------------------------------------------------------------
// beta = sigmoid([t,x,t-x]·w_beta); y = beta*x+(1-beta)*t; powernorm1 -> x1
// ---------------------------------------------------------------------------
__global__ __launch_bounds__(256) void beta_pn1(
    const float* __restrict__ x, const float* __restrict__ tbuf,
    const float* __restrict__ w_beta,
    const float* __restrict__ pw, const float* __restrict__ pb, const float* __restrict__ pphi,
    float* __restrict__ x1)
{
  const int row = blockIdx.x;
  const int tid = threadIdx.x;
  const int c0 = tid * 2;
  const long base = (long)row * CB;
  const float2 xv = *(const float2*)&x[base + c0];
  const float2 tv = *(const float2*)&tbuf[base + c0];
  float p = tv.x * w_beta[c0]   + xv.x * w_beta[CB + c0]   + (tv.x - xv.x) * w_beta[2*CB + c0]
          + tv.y * w_beta[c0+1] + xv.y * w_beta[CB + c0+1] + (tv.y - xv.y) * w_beta[2*CB + c0+1];
  #pragma unroll
  for (int off = 32; off >= 1; off >>= 1) p += __shfl_xor(p, off, 64);
  __shared__ float red[4];
  if ((tid & 63) == 0) red[tid >> 6] = p;
  __syncthreads();
  const float zsum = red[0] + red[1] + red[2] + red[3];
  const float beta = 1.f / (1.f + expf(-zsum));
  const float y0 = beta * xv.x + (1.f - beta) * tv.x;
  const float y1 = beta * xv.y + (1.f - beta) * tv.y;
  float ss = y0*y0 + y1*y1;
  #pragma unroll
  for (int off = 1; off < 16; off <<= 1) ss += __shfl_xor(ss, off, 64);
  const float inv = rsqrtf(ss * (1.f/32.f) + 1e-5f);
  const float o0 = y0 * inv * rsqrtf(pphi[c0]   + 1e-5f) * pw[c0]   + pb[c0];
  const float o1 = y1 * inv * rsqrtf(pphi[c0+1] + 1e-5f) * pw[c0+1] + pb[c0+1];
  *(float2*)&x1[base + c0] = make_float2(o0, o1);
}

// ---------------------------------------------------------------------------
// powernorm2(ffx) -> out
// ---------------------------------------------------------------------------
__global__ __launch_bounds__(256) void pn2_kernel(
    const float* __restrict__ ffx,
    const float* __restrict__ pw, const float* __restrict__ pb, const float* __restrict__ pphi,
    float* __restrict__ out)
{
  const int row = blockIdx.x;
  const int tid = threadIdx.x;
  const int c0 = tid * 2;
  const long base = (long)row * CB;
  const float2 yv = *(const float2*)&ffx[base + c0];
  float ss = yv.x*yv.x + yv.y*yv.y;
  #pragma unroll
  for (int off = 1; off < 16; off <<= 1) ss += __shfl_xor(ss, off, 64);
  const float inv = rsqrtf(ss * (1.f/32.f) + 1e-5f);
  const float o0 = yv.x * inv * rsqrtf(pphi[c0]   + 1e-5f) * pw[c0]   + pb[c0];
  const float o1 = yv.y * inv * rsqrtf(pphi[c0+1] + 1e-5f) * pw[c0+1] + pb[c0+1];
  *(float2*)&out[base + c0] = make_float2(o0, o1);
}

extern "C" void kernel_launch(void* const* d_in, const int* in_sizes, int n_in,
                              void* d_out, int out_size, void* d_ws, size_t ws_size,
                              hipStream_t stream)
{
  const float* x       = (const float*)d_in[0];
  const int*   bi      = (const int*)d_in[1];
  const float* w_qkv   = (const float*)d_in[2];
  const float* w_beta  = (const float*)d_in[3];
  const float* w1      = (const float*)d_in[4];
  const float* b1      = (const float*)d_in[5];
  const float* w2      = (const float*)d_in[6];
  const float* b2      = (const float*)d_in[7];
  const float* pn1_w   = (const float*)d_in[8];
  const float* pn1_b   = (const float*)d_in[9];
  const float* pn1_phi = (const float*)d_in[10];
  const float* pn2_w   = (const float*)d_in[11];
  const float* pn2_b   = (const float*)d_in[12];
  const float* pn2_phi = (const float*)d_in[13];
  float* out = (float*)d_out;
  float* ws  = (float*)d_ws;

  // workspace layout (floats)
  float* qkv   = ws;                               // 4096*1536
  float* segkv = qkv + (long)NL*C3;                // 4*16*16*1024
  float* segk  = segkv + (long)NB*HH*SS*DD*DD;     // 32768
  float* tbuf  = segk + (long)NB*HH*SS*DD;         // 4096*512
  float* x1    = tbuf + (long)NL*CB;               // 4096*512
  float* h1    = qkv;                              // reuse qkv (free after seg_vout)
  float* ffx   = qkv + (long)NL*CB;                // reuse (disjoint from h1)

  gemm_mfma<0,128><<<dim3(NL/128, C3/128), 256, 0, stream>>>(x,  w_qkv, qkv, NL, C3, CB, nullptr, nullptr);
  seg_sums  <<<NB*HH*SS, 256, 0, stream>>>(qkv, bi, segkv, segk);
  seg_vout  <<<NB*HH*SS, 256, 0, stream>>>(qkv, bi, segkv, segk, tbuf);
  beta_pn1  <<<NL, 256, 0, stream>>>(x, tbuf, w_beta, pn1_w, pn1_b, pn1_phi, x1);
  gemm_mfma<1,64><<<dim3(NL/128, CB/64), 256, 0, stream>>>(x1, w1, h1,  NL, CB, CB, b1, nullptr);
  gemm_mfma<2,64><<<dim3(NL/128, CB/64), 256, 0, stream>>>(h1, w2, ffx, NL, CB, CB, b2, x1);
  pn2_kernel<<<NL, 256, 0, stream>>>(ffx, pn2_w, pn2_b, pn2_phi, out);
}

// Round 9
// 223.429 us; speedup vs baseline: 1.2927x; 1.0208x over previous
//
#include <hip/hip_runtime.h>
#include <math.h>

// Problem constants (N,L,C)=(4,1024,512), H=16, D=32, S=16
#define NB 4
#define LB 1024
#define CB 512
#define HH 16
#define DD 32
#define SS 16
#define NL (NB*LB)      // 4096 rows
#define C3 (3*CB)       // 1536

typedef __attribute__((ext_vector_type(8))) short short8;
typedef __attribute__((ext_vector_type(4))) float f32x4;

// global_load_lds: LDS dest = wave-uniform base + lane*16 (HW); global src per-lane.
#define GL16(gp, lp) __builtin_amdgcn_global_load_lds( \
    (const __attribute__((address_space(1))) void*)(gp), \
    (__attribute__((address_space(3))) void*)(lp), 16, 0, 0)

__device__ __forceinline__ unsigned short f2bf_rn(float f) {
  unsigned u = __builtin_bit_cast(unsigned, f);
  unsigned r = u + 0x7FFFu + ((u >> 16) & 1u);
  return (unsigned short)(r >> 16);
}
__device__ __forceinline__ float bf2f(unsigned short h) {
  unsigned u = ((unsigned)h) << 16;
  return __builtin_bit_cast(float, u);
}

__device__ __forceinline__ int lower_bound_i32(const int* a, int n, int v) {
  int lo = 0, hi = n;
  while (lo < hi) { int mid = (lo + hi) >> 1; if (a[mid] < v) lo = mid + 1; else hi = mid; }
  return lo;
}

// ---------------------------------------------------------------------------
// Pre-pass: split fp32 -> (hi,lo) bf16 planes for x, w_qkv, w1, w2.
// ---------------------------------------------------------------------------
#define X4T   524288           // 4096*512/4
#define WQ4T  720896           // + 1536*512/4
#define W14T  786432           // + 512*512/4
#define TOT4  851968           // + 512*512/4
__global__ __launch_bounds__(256) void split_conv(
    const float* __restrict__ x, const float* __restrict__ wqkv,
    const float* __restrict__ w1, const float* __restrict__ w2,
    ushort* __restrict__ xh, ushort* __restrict__ xl,
    ushort* __restrict__ wqh, ushort* __restrict__ wql,
    ushort* __restrict__ w1h, ushort* __restrict__ w1l,
    ushort* __restrict__ w2h, ushort* __restrict__ w2l)
{
  for (int idx = blockIdx.x * 256 + threadIdx.x; idx < TOT4; idx += gridDim.x * 256) {
    const float* src; ushort *dh, *dl; int off;
    if (idx < X4T)        { src = x;    dh = xh;  dl = xl;  off = idx; }
    else if (idx < WQ4T)  { src = wqkv; dh = wqh; dl = wql; off = idx - X4T; }
    else if (idx < W14T)  { src = w1;   dh = w1h; dl = w1l; off = idx - WQ4T; }
    else                  { src = w2;   dh = w2h; dl = w2l; off = idx - W14T; }
    const float4 v = ((const float4*)src)[off];
    ushort4 h, l;
    h.x = f2bf_rn(v.x); l.x = f2bf_rn(v.x - bf2f(h.x));
    h.y = f2bf_rn(v.y); l.y = f2bf_rn(v.y - bf2f(h.y));
    h.z = f2bf_rn(v.z); l.z = f2bf_rn(v.z - bf2f(h.z));
    h.w = f2bf_rn(v.w); l.w = f2bf_rn(v.w - bf2f(h.w));
    ((ushort4*)dh)[off] = h;
    ((ushort4*)dl)[off] = l;
  }
}

// ---------------------------------------------------------------------------
// Split-bf16 MFMA GEMM on pre-split planes. C = epi(sum_k A[m][k]*B[n][k]).
// 128 x BN tile, 4 waves (2x2). LDS slot p = kchunk*ROWS + row, 16B/slot;
// staged via global_load_lds width 16 (linear dest in p-order).
// MODE 0: phi on n<2C, fp32 out | MODE 1: +bias, gelu, hi/lo out | MODE 2:
// +bias + (resh+resl) residual, fp32 out.
// ---------------------------------------------------------------------------
template<int MODE, int BN>
__global__ __launch_bounds__(256) void gemm_mfma2(
    const ushort* __restrict__ Ah, const ushort* __restrict__ Al,
    const ushort* __restrict__ Bh, const ushort* __restrict__ Bl,
    int M, int Nn, int K,
    const float* __restrict__ bias,
    float* __restrict__ Cf, ushort* __restrict__ Ch, ushort* __restrict__ Cl,
    const ushort* __restrict__ resh, const ushort* __restrict__ resl)
{
  constexpr int NJ = BN / 32;
  __shared__ short8 AhL[512], AlL[512];      // 4 kchunks x 128 rows
  __shared__ short8 BhL[4*BN], BlL[4*BN];    // 4 kchunks x BN rows
  const int tid = threadIdx.x;
  const int w = tid >> 6, l = tid & 63;
  const int wm = w >> 1, wn = w & 1;
  const int l15 = l & 15, l4 = l >> 4;
  const int bm = blockIdx.x * 128, bn = blockIdx.y * BN;

  f32x4 acc[4][NJ];
  #pragma unroll
  for (int i = 0; i < 4; ++i)
    #pragma unroll
    for (int j = 0; j < NJ; ++j)
      acc[i][j] = {0.f, 0.f, 0.f, 0.f};

  for (int k0 = 0; k0 < K; k0 += 32) {
    if (k0) __syncthreads();
    #pragma unroll
    for (int i = 0; i < 2; ++i) {          // A: 512 slots, 2 issues/thread/plane
      const int pb = i * 256 + w * 64;
      const int p  = pb + l;
      const long go = (long)(bm + (p & 127)) * K + k0 + (p >> 7) * 8;
      GL16(Ah + go, (char*)AhL + pb * 16);
      GL16(Al + go, (char*)AlL + pb * 16);
    }
    if (BN == 128) {
      #pragma unroll
      for (int i = 0; i < 2; ++i) {
        const int pb = i * 256 + w * 64;
        const int p  = pb + l;
        const long go = (long)(bn + (p & 127)) * K + k0 + (p >> 7) * 8;
        GL16(Bh + go, (char*)BhL + pb * 16);
        GL16(Bl + go, (char*)BlL + pb * 16);
      }
    } else {                                // BN=64: 256 slots, 1 issue
      const int pb = w * 64;
      const int p  = pb + l;
      const long go = (long)(bn + (p & 63)) * K + k0 + (p >> 6) * 8;
      GL16(Bh + go, (char*)BhL + pb * 16);
      GL16(Bl + go, (char*)BlL + pb * 16);
    }
    __syncthreads();   // compiler drains vmcnt before barrier

    short8 bhf[NJ], blf[NJ];
    #pragma unroll
    for (int j = 0; j < NJ; ++j) {
      const int idx = l4 * BN + wn * (NJ * 16) + j * 16 + l15;
      bhf[j] = BhL[idx]; blf[j] = BlL[idx];
    }
    #pragma unroll
    for (int i = 0; i < 4; ++i) {
      const int idx = l4 * 128 + wm * 64 + i * 16 + l15;
      const short8 ah = AhL[idx], al = AlL[idx];
      #pragma unroll
      for (int j = 0; j < NJ; ++j) {
        acc[i][j] = __builtin_amdgcn_mfma_f32_16x16x32_bf16(ah, bhf[j], acc[i][j], 0, 0, 0);
        acc[i][j] = __builtin_amdgcn_mfma_f32_16x16x32_bf16(ah, blf[j], acc[i][j], 0, 0, 0);
        acc[i][j] = __builtin_amdgcn_mfma_f32_16x16x32_bf16(al, bhf[j], acc[i][j], 0, 0, 0);
      }
    }
  }

  const float temp = 0.42044820762685725f;  // 32^-0.25
  #pragma unroll
  for (int i = 0; i < 4; ++i) {
    #pragma unroll
    for (int j = 0; j < NJ; ++j) {
      const int n  = bn + wn * (NJ * 16) + j * 16 + l15;
      const int mb = bm + wm * 64 + i * 16 + l4 * 4;
      #pragma unroll
      for (int r = 0; r < 4; ++r) {
        const int m = mb + r;
        float v = acc[i][j][r];
        if (MODE == 0) {
          if (n < 2 * CB) { const float z = v * temp; v = (z > 0.f) ? (z + 1.f) : expf(z); }
          Cf[(long)m * Nn + n] = v;
        } else if (MODE == 1) {
          v += bias[n];
          v = v * 0.5f * (1.f + erff(v * 0.70710678118654752f));
          const ushort hb = f2bf_rn(v);
          Ch[(long)m * Nn + n] = hb;
          Cl[(long)m * Nn + n] = f2bf_rn(v - bf2f(hb));
        } else {
          const long o = (long)m * Nn + n;
          v += bias[n] + bf2f(resh[o]) + bf2f(resl[o]);
          Cf[o] = v;
        }
      }
    }
  }
}

// ---------------------------------------------------------------------------
// Fused per-(n,h,s) attention: phase 1 builds K_sum[32], KV[32][32] over the
// segment's rows (32-row staged chunks); phase 2 computes
// t[l][m] = (q[l]·KV[:,m]) / (q[l]·K_sum) for the same rows.
// ---------------------------------------------------------------------------
__global__ __launch_bounds__(256) void seg_attn(
    const float* __restrict__ qkv, const int* __restrict__ bi,
    float* __restrict__ tbuf)
{
  const int b = blockIdx.x;               // ((n*H+h)*S+s)
  const int s = b & (SS-1);
  const int h = (b >> 4) & (HH-1);
  const int n = b >> 8;
  __shared__ float ks[32][DD];
  __shared__ float vs[32][DD];
  __shared__ float KVs[DD][DD];
  __shared__ float Ks[DD];
  __shared__ int sb[2];
  const int tid = threadIdx.x;
  if (tid == 0) {
    sb[0] = lower_bound_i32(bi, LB, s);
    sb[1] = lower_bound_i32(bi, LB, s + 1);
  }
  __syncthreads();
  const int lo = sb[0], hi = sb[1];
  const int srow = tid >> 3, sq = tid & 7;       // staging: 32 rows x 8 float4
  const int d = tid >> 3, m0 = (tid & 7) * 4;    // compute roles
  float4 acc = make_float4(0.f, 0.f, 0.f, 0.f);
  float ksum = 0.f;

  for (int l0 = lo; l0 < hi; l0 += 32) {
    const int lr = l0 + srow;
    if (lr < hi) {
      const float* row = qkv + (long)(n*LB + lr) * C3 + h*DD;
      *(float4*)&ks[srow][sq*4] = *(const float4*)(row + CB   + sq*4);
      *(float4*)&vs[srow][sq*4] = *(const float4*)(row + 2*CB + sq*4);
    } else {
      *(float4*)&ks[srow][sq*4] = make_float4(0.f,0.f,0.f,0.f);
      *(float4*)&vs[srow][sq*4] = make_float4(0.f,0.f,0.f,0.f);
    }
    __syncthreads();
    #pragma unroll
    for (int r = 0; r < 32; ++r) {
      const float kd = ks[r][d];
      ksum += kd;
      const float4 vv = *(const float4*)&vs[r][m0];
      acc.x = fmaf(kd, vv.x, acc.x);
      acc.y = fmaf(kd, vv.y, acc.y);
      acc.z = fmaf(kd, vv.z, acc.z);
      acc.w = fmaf(kd, vv.w, acc.w);
    }
    __syncthreads();
  }
  *(float4*)&KVs[d][m0] = acc;
  if ((tid & 7) == 0) Ks[d] = ksum;
  __syncthreads();

  const int prow = tid >> 5, m = tid & 31;       // 8 rows x 32 cols
  for (int l0 = lo; l0 < hi; l0 += 32) {
    const int lr = l0 + srow;
    if (lr < hi)
      *(float4*)&ks[srow][sq*4] = *(const float4*)(qkv + (long)(n*LB + lr) * C3 + h*DD + sq*4);
    __syncthreads();
    #pragma unroll
    for (int step = 0; step < 4; ++step) {
      const int r  = step * 8 + prow;
      const int l2 = l0 + r;
      if (l2 < hi) {
        float vo = 0.f, den = 0.f;
        #pragma unroll
        for (int d2 = 0; d2 < DD; ++d2) {
          const float qd = ks[r][d2];
          vo  = fmaf(qd, KVs[d2][m], vo);
          den = fmaf(qd, Ks[d2], den);
        }
        tbuf[(long)(n*LB + l2) * CB + h*DD + m] = vo / den;
      }
    }
    __syncthreads();
  }
}

// ---------------------------------------------------------------------------
// beta = sigmoid([t,x,t-x]·w_beta); y = beta*x+(1-beta)*t; powernorm1;
// output as hi/lo bf16 planes (consumed by FFN1 A-operand and FFN2 residual).
// ---------------------------------------------------------------------------
__global__ __launch_bounds__(256) void beta_pn1(
    const float* __restrict__ x, const float* __restrict__ tbuf,
    const float* __restrict__ w_beta,
    const float* __restrict__ pw, const float* __restrict__ pb, const float* __restrict__ pphi,
    ushort* __restrict__ x1h, ushort* __restrict__ x1l)
{
  const int row = blockIdx.x;
  const int tid = threadIdx.x;
  const int c0 = tid * 2;
  const long base = (long)row * CB;
  const float2 xv = *(const float2*)&x[base + c0];
  const float2 tv = *(const float2*)&tbuf[base + c0];
  float p = tv.x * w_beta[c0]   + xv.x * w_beta[CB + c0]   + (tv.x - xv.x) * w_beta[2*CB + c0]
          + tv.y * w_beta[c0+1] + xv.y * w_beta[CB + c0+1] + (tv.y - xv.y) * w_beta[2*CB + c0+1];
  #pragma unroll
  for (int off = 32; off >= 1; off >>= 1) p += __shfl_xor(p, off, 64);
  __shared__ float red[4];
  if ((tid & 63) == 0) red[tid >> 6] = p;
  __syncthreads();
  const float zsum = red[0] + red[1] + red[2] + red[3];
  const float beta = 1.f / (1.f + expf(-zsum));
  const float y0 = beta * xv.x + (1.f - beta) * tv.x;
  const float y1 = beta * xv.y + (1.f - beta) * tv.y;
  float ss = y0*y0 + y1*y1;
  #pragma unroll
  for (int off = 1; off < 16; off <<= 1) ss += __shfl_xor(ss, off, 64);  // 16 lanes = 32 ch
  const float inv = rsqrtf(ss * (1.f/32.f) + 1e-5f);
  const float o0 = y0 * inv * rsqrtf(pphi[c0]   + 1e-5f) * pw[c0]   + pb[c0];
  const float o1 = y1 * inv * rsqrtf(pphi[c0+1] + 1e-5f) * pw[c0+1] + pb[c0+1];
  const ushort h0 = f2bf_rn(o0), h1 = f2bf_rn(o1);
  const ushort g0 = f2bf_rn(o0 - bf2f(h0)), g1 = f2bf_rn(o1 - bf2f(h1));
  *(ushort2*)&x1h[base + c0] = make_ushort2(h0, h1);
  *(ushort2*)&x1l[base + c0] = make_ushort2(g0, g1);
}

// ---------------------------------------------------------------------------
// powernorm2(ffx) -> out
// ---------------------------------------------------------------------------
__global__ __launch_bounds__(256) void pn2_kernel(
    const float* __restrict__ ffx,
    const float* __restrict__ pw, const float* __restrict__ pb, const float* __restrict__ pphi,
    float* __restrict__ out)
{
  const int row = blockIdx.x;
  const int tid = threadIdx.x;
  const int c0 = tid * 2;
  const long base = (long)row * CB;
  const float2 yv = *(const float2*)&ffx[base + c0];
  float ss = yv.x*yv.x + yv.y*yv.y;
  #pragma unroll
  for (int off = 1; off < 16; off <<= 1) ss += __shfl_xor(ss, off, 64);
  const float inv = rsqrtf(ss * (1.f/32.f) + 1e-5f);
  const float o0 = yv.x * inv * rsqrtf(pphi[c0]   + 1e-5f) * pw[c0]   + pb[c0];
  const float o1 = yv.y * inv * rsqrtf(pphi[c0+1] + 1e-5f) * pw[c0+1] + pb[c0+1];
  *(float2*)&out[base + c0] = make_float2(o0, o1);
}

extern "C" void kernel_launch(void* const* d_in, const int* in_sizes, int n_in,
                              void* d_out, int out_size, void* d_ws, size_t ws_size,
                              hipStream_t stream)
{
  const float* x       = (const float*)d_in[0];
  const int*   bi      = (const int*)d_in[1];
  const float* w_qkv   = (const float*)d_in[2];
  const float* w_beta  = (const float*)d_in[3];
  const float* w1      = (const float*)d_in[4];
  const float* b1      = (const float*)d_in[5];
  const float* w2      = (const float*)d_in[6];
  const float* b2      = (const float*)d_in[7];
  const float* pn1_w   = (const float*)d_in[8];
  const float* pn1_b   = (const float*)d_in[9];
  const float* pn1_phi = (const float*)d_in[10];
  const float* pn2_w   = (const float*)d_in[11];
  const float* pn2_b   = (const float*)d_in[12];
  const float* pn2_phi = (const float*)d_in[13];
  float* out = (float*)d_out;
  char*  wsb = (char*)d_ws;

  // workspace layout (bytes), total 38,797,312 (< proven 46.3 MB)
  ushort* wqh  = (ushort*)(wsb);                       // 1,572,864 B
  ushort* wql  = (ushort*)(wsb +  1572864);            // 1,572,864
  ushort* w1h  = (ushort*)(wsb +  3145728);            //   524,288
  ushort* w1l  = (ushort*)(wsb +  3670016);
  ushort* w2h  = (ushort*)(wsb +  4194304);
  ushort* w2l  = (ushort*)(wsb +  4718592);
  ushort* xh   = (ushort*)(wsb +  5242880);            // 4,194,304
  ushort* xl   = (ushort*)(wsb +  9437184);            // 4,194,304
  float*  tbuf = (float*) (wsb +  5242880);            // aliases xh/xl (dead after qkv gemm)
  float*  qkvb = (float*) (wsb + 13631488);            // 25,165,824
  // within dead qkv region (after seg_attn):
  ushort* x1h  = (ushort*)(wsb + 13631488);            // 4,194,304
  ushort* x1l  = (ushort*)(wsb + 17825792);            // 4,194,304
  ushort* h1h  = (ushort*)(wsb + 22020096);            // 4,194,304
  ushort* h1l  = (ushort*)(wsb + 26214400);            // 4,194,304
  float*  ffx  = (float*) (wsb + 30408704);            // 8,388,608 -> ends 38,797,312

  split_conv<<<2048, 256, 0, stream>>>(x, w_qkv, w1, w2,
                                       xh, xl, wqh, wql, w1h, w1l, w2h, w2l);
  gemm_mfma2<0,128><<<dim3(NL/128, C3/128), 256, 0, stream>>>(
      xh, xl, wqh, wql, NL, C3, CB, nullptr, qkvb, nullptr, nullptr, nullptr, nullptr);
  seg_attn<<<NB*HH*SS, 256, 0, stream>>>(qkvb, bi, tbuf);
  beta_pn1<<<NL, 256, 0, stream>>>(x, tbuf, w_beta, pn1_w, pn1_b, pn1_phi, x1h, x1l);
  gemm_mfma2<1,64><<<dim3(NL/128, CB/64), 256, 0, stream>>>(
      x1h, x1l, w1h, w1l, NL, CB, CB, b1, nullptr, h1h, h1l, nullptr, nullptr);
  gemm_mfma2<2,64><<<dim3(NL/128, CB/64), 256, 0, stream>>>(
      h1h, h1l, w2h, w2l, NL, CB, CB, b2, ffx, nullptr, nullptr, x1h, x1l);
  pn2_kernel<<<NL, 256, 0, stream>>>(ffx, pn2_w, pn2_b, pn2_phi, out);
}

// Round 14
// 204.245 us; speedup vs baseline: 1.4141x; 1.0939x over previous
//
#include <hip/hip_runtime.h>
#include <math.h>

// Problem constants (N,L,C)=(4,1024,512), H=16, D=32, S=16
#define NB 4
#define LB 1024
#define CB 512
#define HH 16
#define DD 32
#define SS 16
#define NL (NB*LB)      // 4096 rows
#define C3 (3*CB)       // 1536

typedef __attribute__((ext_vector_type(8))) short short8;
typedef __attribute__((ext_vector_type(4))) float f32x4;

// global_load_lds: LDS dest = wave-uniform base + lane*16 (HW); global src per-lane.
#define GL16(gp, lp) __builtin_amdgcn_global_load_lds( \
    (const __attribute__((address_space(1))) void*)(gp), \
    (__attribute__((address_space(3))) void*)(lp), 16, 0, 0)

__device__ __forceinline__ unsigned short f2bf_rn(float f) {
  unsigned u = __builtin_bit_cast(unsigned, f);
  unsigned r = u + 0x7FFFu + ((u >> 16) & 1u);
  return (unsigned short)(r >> 16);
}
__device__ __forceinline__ float bf2f(unsigned short h) {
  unsigned u = ((unsigned)h) << 16;
  return __builtin_bit_cast(float, u);
}

__device__ __forceinline__ int lower_bound_i32(const int* a, int n, int v) {
  int lo = 0, hi = n;
  while (lo < hi) { int mid = (lo + hi) >> 1; if (a[mid] < v) lo = mid + 1; else hi = mid; }
  return lo;
}

// ---------------------------------------------------------------------------
// Pre-pass: split fp32 -> (hi,lo) bf16 planes for x, w_qkv, w1, w2.
// ---------------------------------------------------------------------------
#define X4T   524288           // 4096*512/4
#define WQ4T  720896           // + 1536*512/4
#define W14T  786432           // + 512*512/4
#define TOT4  851968           // + 512*512/4
__global__ __launch_bounds__(256) void split_conv(
    const float* __restrict__ x, const float* __restrict__ wqkv,
    const float* __restrict__ w1, const float* __restrict__ w2,
    ushort* __restrict__ xh, ushort* __restrict__ xl,
    ushort* __restrict__ wqh, ushort* __restrict__ wql,
    ushort* __restrict__ w1h, ushort* __restrict__ w1l,
    ushort* __restrict__ w2h, ushort* __restrict__ w2l)
{
  for (int idx = blockIdx.x * 256 + threadIdx.x; idx < TOT4; idx += gridDim.x * 256) {
    const float* src; ushort *dh, *dl; int off;
    if (idx < X4T)        { src = x;    dh = xh;  dl = xl;  off = idx; }
    else if (idx < WQ4T)  { src = wqkv; dh = wqh; dl = wql; off = idx - X4T; }
    else if (idx < W14T)  { src = w1;   dh = w1h; dl = w1l; off = idx - WQ4T; }
    else                  { src = w2;   dh = w2h; dl = w2l; off = idx - W14T; }
    const float4 v = ((const float4*)src)[off];
    ushort4 h, l;
    h.x = f2bf_rn(v.x); l.x = f2bf_rn(v.x - bf2f(h.x));
    h.y = f2bf_rn(v.y); l.y = f2bf_rn(v.y - bf2f(h.y));
    h.z = f2bf_rn(v.z); l.z = f2bf_rn(v.z - bf2f(h.z));
    h.w = f2bf_rn(v.w); l.w = f2bf_rn(v.w - bf2f(h.w));
    ((ushort4*)dh)[off] = h;
    ((ushort4*)dl)[off] = l;
  }
}

// ---------------------------------------------------------------------------
// Split-bf16 MFMA GEMM, double-buffered LDS prefetch (T3-minimum schedule):
//   stage(buf0); barrier; for t: { stage(buf^1, t+1); ds_read+MFMA(buf);
//   barrier; swap; }
// Prefetch loads fly during ds_read+MFMA; one barrier per K-step.
// BM x BN tile, 4 waves (2x2), per-wave (BM/2)x(BN/2).
// LDS slot p = kchunk*ROWS + row, 16B/slot, linear dest (global_load_lds).
// MODE 0: phi on n<2C, fp32 out | MODE 1: +bias, gelu, hi/lo out | MODE 2:
// +bias + (resh+resl) residual, fp32 out.
// ---------------------------------------------------------------------------
template<int MODE, int BM, int BN>
__global__ __launch_bounds__(256) void gemm_mfma3(
    const ushort* __restrict__ Ah, const ushort* __restrict__ Al,
    const ushort* __restrict__ Bh, const ushort* __restrict__ Bl,
    int M, int Nn, int K,
    const float* __restrict__ bias,
    float* __restrict__ Cf, ushort* __restrict__ Ch, ushort* __restrict__ Cl,
    const ushort* __restrict__ resh, const ushort* __restrict__ resl)
{
  constexpr int MI = BM / 32;          // frag rows per wave
  constexpr int NJ = BN / 32;          // frag cols per wave
  constexpr int ASLOT = BM * 4;        // 16B slots per K-tile (BK=32)
  constexpr int BSLOT = BN * 4;
  __shared__ short8 AhL[2*ASLOT], AlL[2*ASLOT];
  __shared__ short8 BhL[2*BSLOT], BlL[2*BSLOT];
  const int tid = threadIdx.x;
  const int w = tid >> 6, l = tid & 63;
  const int wm = w >> 1, wn = w & 1;
  const int l15 = l & 15, l4 = l >> 4;
  const int bm = blockIdx.x * BM, bn = blockIdx.y * BN;

  f32x4 acc[MI][NJ];
  #pragma unroll
  for (int i = 0; i < MI; ++i)
    #pragma unroll
    for (int j = 0; j < NJ; ++j)
      acc[i][j] = {0.f, 0.f, 0.f, 0.f};

  const int NT = K / 32;

  auto stage = [&](int buf, int k0) {
    #pragma unroll
    for (int i = 0; i < ASLOT/256; ++i) {
      const int pb = buf*ASLOT + i*256 + w*64;     // wave-uniform LDS base slot
      const int p  = i*256 + w*64 + l;             // this lane's slot
      const long go = (long)(bm + (p & (BM-1))) * K + k0 + (p / BM) * 8;
      GL16(Ah + go, (char*)AhL + pb*16);
      GL16(Al + go, (char*)AlL + pb*16);
    }
    #pragma unroll
    for (int i = 0; i < BSLOT/256; ++i) {
      const int pb = buf*BSLOT + i*256 + w*64;
      const int p  = i*256 + w*64 + l;
      const long go = (long)(bn + (p & (BN-1))) * K + k0 + (p / BN) * 8;
      GL16(Bh + go, (char*)BhL + pb*16);
      GL16(Bl + go, (char*)BlL + pb*16);
    }
  };

  stage(0, 0);
  __syncthreads();
  int cur = 0;
  for (int t = 0; t < NT; ++t) {
    if (t + 1 < NT) stage(cur ^ 1, (t + 1) * 32);  // prefetch next K-tile
    short8 bhf[NJ], blf[NJ];
    #pragma unroll
    for (int j = 0; j < NJ; ++j) {
      const int idx = cur*BSLOT + l4*BN + wn*(BN/2) + j*16 + l15;
      bhf[j] = BhL[idx]; blf[j] = BlL[idx];
    }
    #pragma unroll
    for (int i = 0; i < MI; ++i) {
      const int idx = cur*ASLOT + l4*BM + wm*(BM/2) + i*16 + l15;
      const short8 ah = AhL[idx], al = AlL[idx];
      #pragma unroll
      for (int j = 0; j < NJ; ++j) {
        acc[i][j] = __builtin_amdgcn_mfma_f32_16x16x32_bf16(ah, bhf[j], acc[i][j], 0, 0, 0);
        acc[i][j] = __builtin_amdgcn_mfma_f32_16x16x32_bf16(ah, blf[j], acc[i][j], 0, 0, 0);
        acc[i][j] = __builtin_amdgcn_mfma_f32_16x16x32_bf16(al, bhf[j], acc[i][j], 0, 0, 0);
      }
    }
    __syncthreads();   // prefetch complete (vmcnt) + buf[cur] reads done before overwrite
    cur ^= 1;
  }

  const float temp = 0.42044820762685725f;  // 32^-0.25
  #pragma unroll
  for (int i = 0; i < MI; ++i) {
    #pragma unroll
    for (int j = 0; j < NJ; ++j) {
      const int n  = bn + wn * (BN/2) + j * 16 + l15;
      const int mb = bm + wm * (BM/2) + i * 16 + l4 * 4;
      #pragma unroll
      for (int r = 0; r < 4; ++r) {
        const int m = mb + r;
        float v = acc[i][j][r];
        if (MODE == 0) {
          if (n < 2 * CB) { const float z = v * temp; v = (z > 0.f) ? (z + 1.f) : expf(z); }
          Cf[(long)m * Nn + n] = v;
        } else if (MODE == 1) {
          v += bias[n];
          v = v * 0.5f * (1.f + erff(v * 0.70710678118654752f));
          const ushort hb = f2bf_rn(v);
          Ch[(long)m * Nn + n] = hb;
          Cl[(long)m * Nn + n] = f2bf_rn(v - bf2f(hb));
        } else {
          const long o = (long)m * Nn + n;
          v += bias[n] + bf2f(resh[o]) + bf2f(resl[o]);
          Cf[o] = v;
        }
      }
    }
  }
}

// ---------------------------------------------------------------------------
// Fused per-(n,h,s) attention: phase 1 builds K_sum[32], KV[32][32] over the
// segment's rows (32-row staged chunks); phase 2 computes
// t[l][m] = (q[l]·KV[:,m]) / (q[l]·K_sum) for the same rows.
// ---------------------------------------------------------------------------
__global__ __launch_bounds__(256) void seg_attn(
    const float* __restrict__ qkv, const int* __restrict__ bi,
    float* __restrict__ tbuf)
{
  const int b = blockIdx.x;               // ((n*H+h)*S+s)
  const int s = b & (SS-1);
  const int h = (b >> 4) & (HH-1);
  const int n = b >> 8;
  __shared__ float ks[32][DD];
  __shared__ float vs[32][DD];
  __shared__ float KVs[DD][DD];
  __shared__ float Ks[DD];
  __shared__ int sb[2];
  const int tid = threadIdx.x;
  if (tid == 0) {
    sb[0] = lower_bound_i32(bi, LB, s);
    sb[1] = lower_bound_i32(bi, LB, s + 1);
  }
  __syncthreads();
  const int lo = sb[0], hi = sb[1];
  const int srow = tid >> 3, sq = tid & 7;       // staging: 32 rows x 8 float4
  const int d = tid >> 3, m0 = (tid & 7) * 4;    // compute roles
  float4 acc = make_float4(0.f, 0.f, 0.f, 0.f);
  float ksum = 0.f;

  for (int l0 = lo; l0 < hi; l0 += 32) {
    const int lr = l0 + srow;
    if (lr < hi) {
      const float* row = qkv + (long)(n*LB + lr) * C3 + h*DD;
      *(float4*)&ks[srow][sq*4] = *(const float4*)(row + CB   + sq*4);
      *(float4*)&vs[srow][sq*4] = *(const float4*)(row + 2*CB + sq*4);
    } else {
      *(float4*)&ks[srow][sq*4] = make_float4(0.f,0.f,0.f,0.f);
      *(float4*)&vs[srow][sq*4] = make_float4(0.f,0.f,0.f,0.f);
    }
    __syncthreads();
    #pragma unroll
    for (int r = 0; r < 32; ++r) {
      const float kd = ks[r][d];
      ksum += kd;
      const float4 vv = *(const float4*)&vs[r][m0];
      acc.x = fmaf(kd, vv.x, acc.x);
      acc.y = fmaf(kd, vv.y, acc.y);
      acc.z = fmaf(kd, vv.z, acc.z);
      acc.w = fmaf(kd, vv.w, acc.w);
    }
    __syncthreads();
  }
  *(float4*)&KVs[d][m0] = acc;
  if ((tid & 7) == 0) Ks[d] = ksum;
  __syncthreads();

  const int prow = tid >> 5, m = tid & 31;       // 8 rows x 32 cols
  for (int l0 = lo; l0 < hi; l0 += 32) {
    const int lr = l0 + srow;
    if (lr < hi)
      *(float4*)&ks[srow][sq*4] = *(const float4*)(qkv + (long)(n*LB + lr) * C3 + h*DD + sq*4);
    __syncthreads();
    #pragma unroll
    for (int step = 0; step < 4; ++step) {
      const int r  = step * 8 + prow;
      const int l2 = l0 + r;
      if (l2 < hi) {
        float vo = 0.f, den = 0.f;
        #pragma unroll
        for (int d2 = 0; d2 < DD; ++d2) {
          const float qd = ks[r][d2];
          vo  = fmaf(qd, KVs[d2][m], vo);
          den = fmaf(qd, Ks[d2], den);
        }
        tbuf[(long)(n*LB + l2) * CB + h*DD + m] = vo / den;
      }
    }
    __syncthreads();
  }
}

// ---------------------------------------------------------------------------
// beta = sigmoid([t,x,t-x]·w_beta); y = beta*x+(1-beta)*t; powernorm1;
// output as hi/lo bf16 planes (consumed by FFN1 A-operand and FFN2 residual).
// ---------------------------------------------------------------------------
__global__ __launch_bounds__(256) void beta_pn1(
    const float* __restrict__ x, const float* __restrict__ tbuf,
    const float* __restrict__ w_beta,
    const float* __restrict__ pw, const float* __restrict__ pb, const float* __restrict__ pphi,
    ushort* __restrict__ x1h, ushort* __restrict__ x1l)
{
  const int row = blockIdx.x;
  const int tid = threadIdx.x;
  const int c0 = tid * 2;
  const long base = (long)row * CB;
  const float2 xv = *(const float2*)&x[base + c0];
  const float2 tv = *(const float2*)&tbuf[base + c0];
  float p = tv.x * w_beta[c0]   + xv.x * w_beta[CB + c0]   + (tv.x - xv.x) * w_beta[2*CB + c0]
          + tv.y * w_beta[c0+1] + xv.y * w_beta[CB + c0+1] + (tv.y - xv.y) * w_beta[2*CB + c0+1];
  #pragma unroll
  for (int off = 32; off >= 1; off >>= 1) p += __shfl_xor(p, off, 64);
  __shared__ float red[4];
  if ((tid & 63) == 0) red[tid >> 6] = p;
  __syncthreads();
  const float zsum = red[0] + red[1] + red[2] + red[3];
  const float beta = 1.f / (1.f + expf(-zsum));
  const float y0 = beta * xv.x + (1.f - beta) * tv.x;
  const float y1 = beta * xv.y + (1.f - beta) * tv.y;
  float ss = y0*y0 + y1*y1;
  #pragma unroll
  for (int off = 1; off < 16; off <<= 1) ss += __shfl_xor(ss, off, 64);  // 16 lanes = 32 ch
  const float inv = rsqrtf(ss * (1.f/32.f) + 1e-5f);
  const float o0 = y0 * inv * rsqrtf(pphi[c0]   + 1e-5f) * pw[c0]   + pb[c0];
  const float o1 = y1 * inv * rsqrtf(pphi[c0+1] + 1e-5f) * pw[c0+1] + pb[c0+1];
  const ushort h0 = f2bf_rn(o0), h1 = f2bf_rn(o1);
  const ushort g0 = f2bf_rn(o0 - bf2f(h0)), g1 = f2bf_rn(o1 - bf2f(h1));
  *(ushort2*)&x1h[base + c0] = make_ushort2(h0, h1);
  *(ushort2*)&x1l[base + c0] = make_ushort2(g0, g1);
}

// ---------------------------------------------------------------------------
// powernorm2(ffx) -> out
// ---------------------------------------------------------------------------
__global__ __launch_bounds__(256) void pn2_kernel(
    const float* __restrict__ ffx,
    const float* __restrict__ pw, const float* __restrict__ pb, const float* __restrict__ pphi,
    float* __restrict__ out)
{
  const int row = blockIdx.x;
  const int tid = threadIdx.x;
  const int c0 = tid * 2;
  const long base = (long)row * CB;
  const float2 yv = *(const float2*)&ffx[base + c0];
  float ss = yv.x*yv.x + yv.y*yv.y;
  #pragma unroll
  for (int off = 1; off < 16; off <<= 1) ss += __shfl_xor(ss, off, 64);
  const float inv = rsqrtf(ss * (1.f/32.f) + 1e-5f);
  const float o0 = yv.x * inv * rsqrtf(pphi[c0]   + 1e-5f) * pw[c0]   + pb[c0];
  const float o1 = yv.y * inv * rsqrtf(pphi[c0+1] + 1e-5f) * pw[c0+1] + pb[c0+1];
  *(float2*)&out[base + c0] = make_float2(o0, o1);
}

extern "C" void kernel_launch(void* const* d_in, const int* in_sizes, int n_in,
                              void* d_out, int out_size, void* d_ws, size_t ws_size,
                              hipStream_t stream)
{
  const float* x       = (const float*)d_in[0];
  const int*   bi      = (const int*)d_in[1];
  const float* w_qkv   = (const float*)d_in[2];
  const float* w_beta  = (const float*)d_in[3];
  const float* w1      = (const float*)d_in[4];
  const float* b1      = (const float*)d_in[5];
  const float* w2      = (const float*)d_in[6];
  const float* b2      = (const float*)d_in[7];
  const float* pn1_w   = (const float*)d_in[8];
  const float* pn1_b   = (const float*)d_in[9];
  const float* pn1_phi = (const float*)d_in[10];
  const float* pn2_w   = (const float*)d_in[11];
  const float* pn2_b   = (const float*)d_in[12];
  const float* pn2_phi = (const float*)d_in[13];
  float* out = (float*)d_out;
  char*  wsb = (char*)d_ws;

  // workspace layout (bytes), total 38,797,312 (< proven 46.3 MB)
  ushort* wqh  = (ushort*)(wsb);                       // 1,572,864 B
  ushort* wql  = (ushort*)(wsb +  1572864);            // 1,572,864
  ushort* w1h  = (ushort*)(wsb +  3145728);            //   524,288
  ushort* w1l  = (ushort*)(wsb +  3670016);
  ushort* w2h  = (ushort*)(wsb +  4194304);
  ushort* w2l  = (ushort*)(wsb +  4718592);
  ushort* xh   = (ushort*)(wsb +  5242880);            // 4,194,304
  ushort* xl   = (ushort*)(wsb +  9437184);            // 4,194,304
  float*  tbuf = (float*) (wsb +  5242880);            // aliases xh/xl (dead after qkv gemm)
  float*  qkvb = (float*) (wsb + 13631488);            // 25,165,824
  // within dead qkv region (after seg_attn):
  ushort* x1h  = (ushort*)(wsb + 13631488);            // 4,194,304
  ushort* x1l  = (ushort*)(wsb + 17825792);            // 4,194,304
  ushort* h1h  = (ushort*)(wsb + 22020096);            // 4,194,304
  ushort* h1l  = (ushort*)(wsb + 26214400);            // 4,194,304
  float*  ffx  = (float*) (wsb + 30408704);            // 8,388,608 -> ends 38,797,312

  split_conv<<<2048, 256, 0, stream>>>(x, w_qkv, w1, w2,
                                       xh, xl, wqh, wql, w1h, w1l, w2h, w2l);
  gemm_mfma3<0,128,128><<<dim3(NL/128, C3/128), 256, 0, stream>>>(
      xh, xl, wqh, wql, NL, C3, CB, nullptr, qkvb, nullptr, nullptr, nullptr, nullptr);
  seg_attn<<<NB*HH*SS, 256, 0, stream>>>(qkvb, bi, tbuf);
  beta_pn1<<<NL, 256, 0, stream>>>(x, tbuf, w_beta, pn1_w, pn1_b, pn1_phi, x1h, x1l);
  gemm_mfma3<1,64,64><<<dim3(NL/64, CB/64), 256, 0, stream>>>(
      x1h, x1l, w1h, w1l, NL, CB, CB, b1, nullptr, h1h, h1l, nullptr, nullptr);
  gemm_mfma3<2,64,64><<<dim3(NL/64, CB/64), 256, 0, stream>>>(
      h1h, h1l, w2h, w2l, NL, CB, CB, b2, ffx, nullptr, nullptr, x1h, x1l);
  pn2_kernel<<<NL, 256, 0, stream>>>(ffx, pn2_w, pn2_b, pn2_phi, out);
}